// Round 1
// 1625.523 us; speedup vs baseline: 1.0190x; 1.0190x over previous
//
#include <hip/hip_runtime.h>

// Problem constants (match reference)
#define NHEAD   16
#define DK      64
#define DMODEL  1024
#define BSZ     2
#define SEQLEN  1024
#define NI      64
#define NN2     1088          // SEQLEN + NI
#define NBUCK   9             // N_B + 1
#define TOPK    16

#define T_ITEM  (BSZ*SEQLEN)  // 2048 item tokens
#define T_INT   (BSZ*NN2)     // 2176 intent tokens

// workspace layout (bytes). total ~26.4 MB
#define Q_OFF   ((size_t)0)                          // q: 2048x1024 f32
#define K_OFF   (Q_OFF + (size_t)T_ITEM*DMODEL*4)    // k: 2176x1024 f32
#define V_OFF   (K_OFF + (size_t)T_INT*DMODEL*4)     // v: 2176x1024 f32
#define CNT_OFF (V_OFF + (size_t)T_INT*DMODEL*4)     // counts: 18 ints
#define LI_OFF  (CNT_OFF + 128)                      // item lists 9x2048
#define LN_OFF  (LI_OFF + (size_t)NBUCK*T_ITEM*4)    // intent lists 9x2176
#define WS_NEED (LN_OFF + (size_t)NBUCK*T_INT*4)

// fp64 sidecar buffers live INSIDE the V region (used before v-GEMM writes it):
//   q0d: 2048*64 f64 (1 MB), k0d: 2176*64 f64 (1.1 MB)  — V region is 8.9 MB.
#define Q0D_OFF V_OFF
#define K0D_OFF (V_OFF + (size_t)T_ITEM*64*8)

#define X_OUT_ELEMS ((size_t)BSZ*SEQLEN*DMODEL)      // 2,097,152
#define SIDX_ELEMS  ((size_t)BSZ*SEQLEN)             // 2048

__device__ __forceinline__ int clampi(int v, int lo, int hi) {
  return v < lo ? lo : (v > hi ? hi : v);
}

// ---------------------------------------------------------------------------
// Kernel 1: counting-sort tokens into buckets (order within bucket irrelevant)
// ---------------------------------------------------------------------------
__global__ void bucketize_kernel(const int* __restrict__ b_seq, const int* __restrict__ b_seq2,
                                 int* __restrict__ cnt, int* __restrict__ list_item,
                                 int* __restrict__ list_int) {
  int t = blockIdx.x * blockDim.x + threadIdx.x;
  if (t < T_ITEM) {
    int B = clampi(b_seq[t], 0, NBUCK - 1);
    int p = atomicAdd(&cnt[B], 1);
    if (p >= 0 && p < T_ITEM) list_item[B * T_ITEM + p] = t;
  }
  if (t < T_INT) {
    int B = clampi(b_seq2[t], 0, NBUCK - 1);
    int p = atomicAdd(&cnt[NBUCK + B], 1);
    if (p >= 0 && p < T_INT) list_int[B * T_INT + p] = t;
  }
}

// ---------------------------------------------------------------------------
// fp64 sidecar A: head-0 projection  Y[tok][k] = sum_d X[tok][d]*W[B][d][k]
// (k = 0..63 = head 0 columns). One wave per token; lane = k. Reads b_seq
// directly — independent of the bucketize/list path.
// ---------------------------------------------------------------------------
__global__ __launch_bounds__(256) void proj_head0_f64(
    const float* __restrict__ X, const float* __restrict__ W,
    const int* __restrict__ bseq, double* __restrict__ Y, const int T) {
  const int wave = (int)threadIdx.x >> 6, lane = (int)threadIdx.x & 63;
  const int tok = blockIdx.x * 4 + wave;
  if (tok >= T) return;
  const int B = clampi(bseq[tok], 0, NBUCK - 1);
  const float* xr = X + (size_t)tok * DMODEL;
  const float* wb = W + (size_t)B * DMODEL * (NHEAD * DK) + lane;  // W[B][d][lane]
  double acc = 0.0;
  #pragma unroll 4
  for (int d = 0; d < DMODEL; ++d)
    acc += (double)xr[d] * (double)wb[(size_t)d * (NHEAD * DK)];
  Y[(size_t)tok * 64 + lane] = acc;
}

// ---------------------------------------------------------------------------
// fp64 sidecar B: per q-row fp64 scores over all 1088 keys; exact
// first-occurrence argmax over [0,1024) -> sIdx and [1024,1088) -> aIdx.
// softmax is monotone -> argmax(p) == argmax(scores); /sqrt(64) scaling
// does not affect ordering. One block (256 thr) per q-row.
// ---------------------------------------------------------------------------
__global__ __launch_bounds__(256) void argmax_f64(
    const double* __restrict__ Q0, const double* __restrict__ K0,
    float* __restrict__ out_s, float* __restrict__ out_a) {
  const int n = blockIdx.x;          // b*1024 + nn
  const int b = n >> 10;
  const int t = (int)threadIdx.x;
  __shared__ double qs[64];
  __shared__ double bval[256];  __shared__ int bidx[256];
  __shared__ double bval2[256]; __shared__ int bidx2[256];
  if (t < 64) qs[t] = Q0[(size_t)n * 64 + t];
  __syncthreads();
  double v1 = -1e300; int i1 = 0x7FFFFFFF;
  double v2 = -1e300; int i2 = 0x7FFFFFFF;
  for (int m = t; m < NN2; m += 256) {
    const double* kr = K0 + (size_t)(b * NN2 + m) * 64;
    double s = 0.0;
    #pragma unroll 8
    for (int k = 0; k < 64; ++k) s += qs[k] * kr[k];
    if (m < 1024) { if (s > v1 || (s == v1 && m < i1)) { v1 = s; i1 = m; } }
    else          { if (s > v2 || (s == v2 && m < i2)) { v2 = s; i2 = m; } }
  }
  bval[t] = v1; bidx[t] = i1; bval2[t] = v2; bidx2[t] = i2;
  __syncthreads();
  for (int off = 128; off >= 1; off >>= 1) {
    if (t < off) {
      if (bval[t+off] >  bval[t] || (bval[t+off] ==  bval[t] &&  bidx[t+off] <  bidx[t])) { bval[t]  = bval[t+off];  bidx[t]  = bidx[t+off]; }
      if (bval2[t+off] > bval2[t] || (bval2[t+off] == bval2[t] && bidx2[t+off] < bidx2[t])) { bval2[t] = bval2[t+off]; bidx2[t] = bidx2[t+off]; }
    }
    __syncthreads();
  }
  if (t == 0) {
    out_s[n] = (float)bidx[0];
    out_a[n] = (float)(bidx2[0] - 1024);
  }
}

// ---------------------------------------------------------------------------
// Kernel 2: grouped GEMM  Y[tok] = X[tok] @ W[bucket(tok)]  (fp32)
// tile 128x128, BK=16, 256 threads, 8x8 micro-tile per thread
// ---------------------------------------------------------------------------
#define TM  128
#define TN  128
#define GBK 16

__global__ __launch_bounds__(256) void gemm_grouped(
    const float* __restrict__ X, const float* __restrict__ W,
    const int* __restrict__ list, const int* __restrict__ cnt,
    float* __restrict__ Y, const int Tmax) {
  const int B = blockIdx.z;
  const int n = min(cnt[B], Tmax);       // defensive clamp
  const int row0 = blockIdx.y * TM;
  if (row0 >= n) return;                 // uniform across block: no divergent barrier
  const int rows = min(TM, n - row0);
  const int c0 = blockIdx.x * TN;
  const int t = (int)threadIdx.x;

  __shared__ float Xs[GBK][TM + 4];   // k-major (transposed on store)
  __shared__ float Ws[GBK][TN + 4];

  const int tokA = t >> 1;            // 0..127
  const int kqA  = (t & 1) * 8;       // 0 or 8
  const int liA  = clampi(list[row0 + min(tokA, rows - 1)], 0, Tmax - 1);
  const float* xrow = X + (size_t)liA * DMODEL;
  const int kW = t >> 4;              // 0..15
  const int cW = (t & 15) * 8;        // 0..120

  const int ty = t >> 4;              // row group (8 rows)
  const int tx = t & 15;              // col group (8 cols)

  float acc[8][8];
  #pragma unroll
  for (int i = 0; i < 8; ++i)
    #pragma unroll
    for (int j = 0; j < 8; ++j) acc[i][j] = 0.f;

  for (int k0 = 0; k0 < DMODEL; k0 += GBK) {
    float4 xa = *(const float4*)(xrow + k0 + kqA);
    float4 xb = *(const float4*)(xrow + k0 + kqA + 4);
    const float* wp = W + ((size_t)B * DMODEL + k0 + kW) * (size_t)(NHEAD * DK) + c0 + cW;
    float4 wa = *(const float4*)wp;
    float4 wb = *(const float4*)(wp + 4);

    Xs[kqA + 0][tokA] = xa.x; Xs[kqA + 1][tokA] = xa.y;
    Xs[kqA + 2][tokA] = xa.z; Xs[kqA + 3][tokA] = xa.w;
    Xs[kqA + 4][tokA] = xb.x; Xs[kqA + 5][tokA] = xb.y;
    Xs[kqA + 6][tokA] = xb.z; Xs[kqA + 7][tokA] = xb.w;
    *(float4*)&Ws[kW][cW]     = wa;
    *(float4*)&Ws[kW][cW + 4] = wb;
    __syncthreads();

    #pragma unroll
    for (int kk = 0; kk < GBK; ++kk) {
      float a[8], bv[8];
      *(float4*)&a[0]  = *(const float4*)&Xs[kk][ty * 8];
      *(float4*)&a[4]  = *(const float4*)&Xs[kk][ty * 8 + 4];
      *(float4*)&bv[0] = *(const float4*)&Ws[kk][tx * 8];
      *(float4*)&bv[4] = *(const float4*)&Ws[kk][tx * 8 + 4];
      #pragma unroll
      for (int i = 0; i < 8; ++i)
        #pragma unroll
        for (int j = 0; j < 8; ++j)
          acc[i][j] = fmaf(a[i], bv[j], acc[i][j]);
    }
    __syncthreads();
  }

  #pragma unroll
  for (int i = 0; i < 8; ++i) {
    const int r = ty * 8 + i;
    if (r < rows) {
      const int tok = clampi(list[row0 + r], 0, Tmax - 1);
      float* yr = Y + (size_t)tok * (size_t)(NHEAD * DK) + c0 + tx * 8;
      float4 o0 = make_float4(acc[i][0], acc[i][1], acc[i][2], acc[i][3]);
      float4 o1 = make_float4(acc[i][4], acc[i][5], acc[i][6], acc[i][7]);
      *(float4*)yr       = o0;
      *(float4*)(yr + 4) = o1;
    }
  }
}

// ---------------------------------------------------------------------------
// Kernel 3: fused attention: scores -> softmax -> exact top-16 per segment ->
//           sparse p@V.  (index outputs come from the fp64 sidecar)
// Block = 256 thr (4 waves), 16 q-rows per block (4 per wave).
//
// VALU-cut rewrite vs previous version:
//  * score loop: q broadcast via wave-uniform LDS reads (free broadcast on the
//    lgkm pipe) instead of one v_readlane per FMA  -> 1 VALU/element.
//  * top-k: (value,index) packed into one u64 key (monotone f32->u32 map in
//    hi, ~index in lo) -> butterfly argmax step = 1 v_cmp_u64 + 2 cndmask.
//    Tiebreak (max value, then min index) preserved exactly.
//  * __launch_bounds__(256,3): ~170 VGPR budget so the 68 live score floats
//    stay in arch VGPRs (previous build: 56 VGPR + AGPR spill churn).
// Score accumulation order is bitwise identical to the previous version.
// ---------------------------------------------------------------------------
__device__ __forceinline__ unsigned ordf(float v) {
  // monotone map f32 -> u32 (total order, -inf..+inf ascending)
  unsigned s = __float_as_uint(v);
  return s ^ ((unsigned)((int)s >> 31) | 0x80000000u);
}
__device__ __forceinline__ float unordf(unsigned u) {
  unsigned s = (u & 0x80000000u) ? (u ^ 0x80000000u) : ~u;
  return __uint_as_float(s);
}
__device__ __forceinline__ unsigned long long bfly_max_u64(unsigned long long w) {
  #pragma unroll
  for (int off = 1; off < 64; off <<= 1) {
    unsigned lo = __shfl_xor((unsigned)w, off);
    unsigned hi = __shfl_xor((unsigned)(w >> 32), off);
    unsigned long long o = ((unsigned long long)hi << 32) | lo;
    w = (o > w) ? o : w;
  }
  return w;
}

__global__ __launch_bounds__(256, 3) void attn_kernel(
    const float* __restrict__ Q, const float* __restrict__ K,
    const float* __restrict__ V, float* __restrict__ outx) {
  const int b = blockIdx.z, h = blockIdx.y;
  const int n0 = blockIdx.x * 16;
  const int t = (int)threadIdx.x;
  const int wave = t >> 6, lane = t & 63;

  __shared__ float Qs[16][64];
  __shared__ float Ks[64][68];        // +4 pad: conflict-free b128
  __shared__ int   kept_m[16][32];
  __shared__ float kept_p[16][32];

  {
    const int r = t >> 4, k4 = (t & 15) * 4;
    *(float4*)&Qs[r][k4] =
        *(const float4*)(Q + (size_t)(b * SEQLEN + n0 + r) * (NHEAD * DK) + h * DK + k4);
  }
  __syncthreads();

  const int r0 = wave * 4;
  float s0[17], s1[17], s2[17], s3[17];   // score at m = c*64 + lane

  for (int c = 0; c < 17; ++c) {
    if (c > 0) __syncthreads();
    #pragma unroll
    for (int j = 0; j < 4; ++j) {
      const int row = (t >> 4) + 16 * j;
      const int k4 = (t & 15) * 4;
      *(float4*)&Ks[row][k4] =
          *(const float4*)(K + (size_t)(b * NN2 + c * 64 + row) * (NHEAD * DK) + h * DK + k4);
    }
    __syncthreads();

    float a0 = 0.f, a1 = 0.f, a2 = 0.f, a3 = 0.f;
    #pragma unroll 4
    for (int k4 = 0; k4 < 64; k4 += 4) {
      const float4 kv = *(const float4*)&Ks[lane][k4];
      const float4 q0 = *(const float4*)&Qs[r0 + 0][k4];   // wave-uniform: LDS broadcast
      const float4 q1 = *(const float4*)&Qs[r0 + 1][k4];
      const float4 q2 = *(const float4*)&Qs[r0 + 2][k4];
      const float4 q3 = *(const float4*)&Qs[r0 + 3][k4];
      a0 = fmaf(q0.x, kv.x, a0); a0 = fmaf(q0.y, kv.y, a0);
      a0 = fmaf(q0.z, kv.z, a0); a0 = fmaf(q0.w, kv.w, a0);
      a1 = fmaf(q1.x, kv.x, a1); a1 = fmaf(q1.y, kv.y, a1);
      a1 = fmaf(q1.z, kv.z, a1); a1 = fmaf(q1.w, kv.w, a1);
      a2 = fmaf(q2.x, kv.x, a2); a2 = fmaf(q2.y, kv.y, a2);
      a2 = fmaf(q2.z, kv.z, a2); a2 = fmaf(q2.w, kv.w, a2);
      a3 = fmaf(q3.x, kv.x, a3); a3 = fmaf(q3.y, kv.y, a3);
      a3 = fmaf(q3.z, kv.z, a3); a3 = fmaf(q3.w, kv.w, a3);
    }
    s0[c] = a0 * 0.125f; s1[c] = a1 * 0.125f;
    s2[c] = a2 * 0.125f; s3[c] = a3 * 0.125f;
  }

  auto process_row = [&](const float (&sv)[17], const int rr) {
    const int r_loc = wave * 4 + rr;
    float M = -3.402823466e38f;
    #pragma unroll
    for (int c = 0; c < 17; ++c) M = fmaxf(M, sv[c]);
    #pragma unroll
    for (int off = 32; off >= 1; off >>= 1) M = fmaxf(M, __shfl_xor(M, off));
    float L = 0.f;
    #pragma unroll
    for (int c = 0; c < 17; ++c) L += __expf(sv[c] - M);
    #pragma unroll
    for (int off = 32; off >= 1; off >>= 1) L += __shfl_xor(L, off);
    const float invL = 1.0f / L;

    // ---- segment 1: top-16 of m in [0,1024), packed-u64 extraction ----
    unsigned kh[16];
    #pragma unroll
    for (int c = 0; c < 16; ++c) kh[c] = ordf(sv[c]);
    unsigned alive = 0xFFFFu;
    unsigned long long best = 0ull;
    #pragma unroll
    for (int c = 0; c < 16; ++c) {
      unsigned long long k64 =
          ((unsigned long long)kh[c] << 32) | (unsigned)~(unsigned)(c * 64 + lane);
      best = (k64 > best) ? k64 : best;
    }
    for (int round = 0; round < TOPK; ++round) {
      const unsigned long long w = bfly_max_u64(best);
      const int m = (int)(~(unsigned)w) & 1023;
      if (lane == round) {
        kept_m[r_loc][round] = m;
        kept_p[r_loc][round] = __expf(unordf((unsigned)(w >> 32)) - M) * invL;
      }
      if ((m & 63) == lane) {          // winner lane: kill chunk, lazy recompute
        alive &= ~(1u << (m >> 6));
        best = 0ull;
        #pragma unroll
        for (int c = 0; c < 16; ++c) {
          if (alive & (1u << c)) {
            unsigned long long k64 =
                ((unsigned long long)kh[c] << 32) | (unsigned)~(unsigned)(c * 64 + lane);
            best = (k64 > best) ? k64 : best;
          }
        }
      }
    }

    // ---- segment 2: top-16 of the NI=64 tail (one candidate per lane) ----
    unsigned long long cand =
        ((unsigned long long)ordf(sv[16]) << 32) | (unsigned)~(unsigned)lane;
    for (int round = 0; round < TOPK; ++round) {
      const unsigned long long w = bfly_max_u64(cand);
      const int l2 = (int)(~(unsigned)w) & 63;
      if (lane == round) {
        kept_m[r_loc][TOPK + round] = 1024 + l2;
        kept_p[r_loc][TOPK + round] = __expf(unordf((unsigned)(w >> 32)) - M) * invL;
      }
      if (l2 == lane) cand = 0ull;
    }
  };
  process_row(s0, 0); process_row(s1, 1); process_row(s2, 2); process_row(s3, 3);
  __syncthreads();

  #pragma unroll
  for (int rr = 0; rr < 4; ++rr) {
    const int r_loc = wave * 4 + rr;
    const int n = n0 + r_loc;
    float x = 0.f;
    #pragma unroll
    for (int i = 0; i < 32; ++i) {
      const int m = clampi(kept_m[r_loc][i], 0, NN2 - 1);
      const float p = kept_p[r_loc][i];
      x = fmaf(p, V[(size_t)(b * NN2 + m) * (NHEAD * DK) + h * DK + lane], x);
    }
    outx[(size_t)(b * SEQLEN + n) * (NHEAD * DK) + h * DK + lane] = x;
  }
}

// ---------------------------------------------------------------------------
extern "C" void kernel_launch(void* const* d_in, const int* in_sizes, int n_in,
                              void* d_out, int out_size, void* d_ws, size_t ws_size,
                              hipStream_t stream) {
  const float* item    = (const float*)d_in[0];
  const float* intent  = (const float*)d_in[1];
  // d_in[2] = mask: constant all-True -> no-op, skipped
  const int*   b_seq   = (const int*)d_in[3];
  const int*   b_seq2  = (const int*)d_in[4];
  const float* W_item  = (const float*)d_in[5];   // [9][1024][16][64]
  const float* W_int   = (const float*)d_in[6];   // [2][9][1024][16][64]

  if (ws_size < WS_NEED) return;   // clean failure instead of device fault

  char* ws = (char*)d_ws;
  float* qb = (float*)(ws + Q_OFF);
  float* kb = (float*)(ws + K_OFF);
  float* vb = (float*)(ws + V_OFF);
  double* q0d = (double*)(ws + Q0D_OFF);   // aliases V region (used before v-GEMM)
  double* k0d = (double*)(ws + K0D_OFF);
  int* cnt       = (int*)(ws + CNT_OFF);
  int* list_item = (int*)(ws + LI_OFF);
  int* list_int  = (int*)(ws + LN_OFF);

  float* outx  = (float*)d_out;
  float* out_s = outx + X_OUT_ELEMS;
  float* out_a = out_s + SIDX_ELEMS;

  hipMemsetAsync(cnt, 0, 128, stream);
  bucketize_kernel<<<dim3(9), 256, 0, stream>>>(b_seq, b_seq2, cnt, list_item, list_int);

  // fp64 sidecar: head-0 q/k projections + exact argmax -> sIdx, aIdx.
  // Uses the V workspace region BEFORE the v-GEMM overwrites it.
  proj_head0_f64<<<dim3((T_ITEM + 3) / 4), 256, 0, stream>>>(item, W_item, b_seq, q0d, T_ITEM);
  proj_head0_f64<<<dim3((T_INT + 3) / 4), 256, 0, stream>>>(intent, W_int, b_seq2, k0d, T_INT);
  argmax_f64<<<dim3(T_ITEM), 256, 0, stream>>>(q0d, k0d, out_s, out_a);

  // fp32 pipeline for x
  gemm_grouped<<<dim3(8, 16, 9), 256, 0, stream>>>(item, W_item, list_item, cnt, qb, T_ITEM);
  gemm_grouped<<<dim3(8, 17, 9), 256, 0, stream>>>(intent, W_int, list_int, cnt + NBUCK, kb, T_INT);
  gemm_grouped<<<dim3(8, 17, 9), 256, 0, stream>>>(intent, W_int + (size_t)NBUCK * DMODEL * (NHEAD * DK),
                                                   list_int, cnt + NBUCK, vb, T_INT);

  attn_kernel<<<dim3(SEQLEN / 16, NHEAD, BSZ), 256, 0, stream>>>(qb, kb, vb, outx);
}

// Round 2
// 1006.405 us; speedup vs baseline: 1.6458x; 1.6152x over previous
//
#include <hip/hip_runtime.h>

// Problem constants (match reference)
#define NHEAD   16
#define DK      64
#define DMODEL  1024
#define BSZ     2
#define SEQLEN  1024
#define NI      64
#define NN2     1088          // SEQLEN + NI
#define NBUCK   9             // N_B + 1
#define TOPK    16

#define T_ITEM  (BSZ*SEQLEN)  // 2048 item tokens
#define T_INT   (BSZ*NN2)     // 2176 intent tokens

// workspace layout (bytes). total ~26.4 MB
#define Q_OFF   ((size_t)0)                          // q: 2048x1024 f32
#define K_OFF   (Q_OFF + (size_t)T_ITEM*DMODEL*4)    // k: 2176x1024 f32
#define V_OFF   (K_OFF + (size_t)T_INT*DMODEL*4)     // v: 2176x1024 f32
#define CNT_OFF (V_OFF + (size_t)T_INT*DMODEL*4)     // counts: 18 ints
#define LI_OFF  (CNT_OFF + 128)                      // item lists 9x2048
#define LN_OFF  (LI_OFF + (size_t)NBUCK*T_ITEM*4)    // intent lists 9x2176
#define WS_NEED (LN_OFF + (size_t)NBUCK*T_INT*4)

// fp64 sidecar buffers live INSIDE the V region (used before v-GEMM writes it):
//   q0d: 2048*64 f64 row-major (1 MB), k0dT: 64 x 2176 f64 TRANSPOSED (1.1 MB)
#define Q0D_OFF V_OFF
#define K0D_OFF (V_OFF + (size_t)T_ITEM*64*8)

#define X_OUT_ELEMS ((size_t)BSZ*SEQLEN*DMODEL)      // 2,097,152
#define SIDX_ELEMS  ((size_t)BSZ*SEQLEN)             // 2048

__device__ __forceinline__ int clampi(int v, int lo, int hi) {
  return v < lo ? lo : (v > hi ? hi : v);
}

// ---------------------------------------------------------------------------
// Kernel 1: counting-sort tokens into buckets (order within bucket irrelevant)
// ---------------------------------------------------------------------------
__global__ void bucketize_kernel(const int* __restrict__ b_seq, const int* __restrict__ b_seq2,
                                 int* __restrict__ cnt, int* __restrict__ list_item,
                                 int* __restrict__ list_int) {
  int t = blockIdx.x * blockDim.x + threadIdx.x;
  if (t < T_ITEM) {
    int B = clampi(b_seq[t], 0, NBUCK - 1);
    int p = atomicAdd(&cnt[B], 1);
    if (p >= 0 && p < T_ITEM) list_item[B * T_ITEM + p] = t;
  }
  if (t < T_INT) {
    int B = clampi(b_seq2[t], 0, NBUCK - 1);
    int p = atomicAdd(&cnt[NBUCK + B], 1);
    if (p >= 0 && p < T_INT) list_int[B * T_INT + p] = t;
  }
}

// ---------------------------------------------------------------------------
// fp64 sidecar A: head-0 projection  Y[tok][k] = sum_d X[tok][d]*W[B][d][k]
// transposed=0: Y[tok*64 + k] (row-major, for Q0)
// transposed=1: Y[k*T + tok]  (k-major, so argmax reads are lane-coalesced)
// ---------------------------------------------------------------------------
__global__ __launch_bounds__(256) void proj_head0_f64(
    const float* __restrict__ X, const float* __restrict__ W,
    const int* __restrict__ bseq, double* __restrict__ Y, const int T,
    const int transposed) {
  const int wave = (int)threadIdx.x >> 6, lane = (int)threadIdx.x & 63;
  const int tok = blockIdx.x * 4 + wave;
  if (tok >= T) return;
  const int B = clampi(bseq[tok], 0, NBUCK - 1);
  const float* xr = X + (size_t)tok * DMODEL;
  const float* wb = W + (size_t)B * DMODEL * (NHEAD * DK) + lane;  // W[B][d][lane]
  double acc = 0.0;
  #pragma unroll 4
  for (int d = 0; d < DMODEL; ++d)
    acc += (double)xr[d] * (double)wb[(size_t)d * (NHEAD * DK)];
  if (transposed) Y[(size_t)lane * T + tok] = acc;
  else            Y[(size_t)tok * 64 + lane] = acc;
}

// ---------------------------------------------------------------------------
// fp64 sidecar B: per q-row fp64 scores over all 1088 keys; exact
// first-occurrence argmax over [0,1024) -> sIdx and [1024,1088) -> aIdx.
// K0 is TRANSPOSED [64][T_INT]: inner k loop reads lanes-consecutive m ->
// fully coalesced 512B/wave loads (prev: 64-line scatter per load).
// ---------------------------------------------------------------------------
__global__ __launch_bounds__(256) void argmax_f64(
    const double* __restrict__ Q0, const double* __restrict__ K0T,
    float* __restrict__ out_s, float* __restrict__ out_a) {
  const int n = blockIdx.x;          // b*1024 + nn
  const int b = n >> 10;
  const int t = (int)threadIdx.x;
  __shared__ double qs[64];
  __shared__ double bval[256];  __shared__ int bidx[256];
  __shared__ double bval2[256]; __shared__ int bidx2[256];
  if (t < 64) qs[t] = Q0[(size_t)n * 64 + t];
  __syncthreads();
  double v1 = -1e300; int i1 = 0x7FFFFFFF;
  double v2 = -1e300; int i2 = 0x7FFFFFFF;
  for (int m = t; m < NN2; m += 256) {
    const double* base = K0T + (size_t)b * NN2 + m;   // column m of K0T
    double s = 0.0;
    #pragma unroll 8
    for (int k = 0; k < 64; ++k) s += qs[k] * base[(size_t)k * T_INT];
    if (m < 1024) { if (s > v1 || (s == v1 && m < i1)) { v1 = s; i1 = m; } }
    else          { if (s > v2 || (s == v2 && m < i2)) { v2 = s; i2 = m; } }
  }
  bval[t] = v1; bidx[t] = i1; bval2[t] = v2; bidx2[t] = i2;
  __syncthreads();
  for (int off = 128; off >= 1; off >>= 1) {
    if (t < off) {
      if (bval[t+off] >  bval[t] || (bval[t+off] ==  bval[t] &&  bidx[t+off] <  bidx[t])) { bval[t]  = bval[t+off];  bidx[t]  = bidx[t+off]; }
      if (bval2[t+off] > bval2[t] || (bval2[t+off] == bval2[t] && bidx2[t+off] < bidx2[t])) { bval2[t] = bval2[t+off]; bidx2[t] = bidx2[t+off]; }
    }
    __syncthreads();
  }
  if (t == 0) {
    out_s[n] = (float)bidx[0];
    out_a[n] = (float)(bidx2[0] - 1024);
  }
}

// ---------------------------------------------------------------------------
// Kernel 2: FUSED grouped GEMM for q,k,v in one launch.
// blockIdx.z = g*9 + bucket, g=0:q(item,W_item) 1:k(intent,W_int[0]) 2:v(W_int[1])
// tile 128x128, BK=16, 512 threads (8 waves, 2/SIMD), 8x4 micro-tile.
// Same kk/k0 FMA order per output as previous version -> bitwise identical.
// ---------------------------------------------------------------------------
#define TM  128
#define TN  128
#define GBK 16

__global__ __launch_bounds__(512) void gemm_grouped_fused(
    const float* __restrict__ item, const float* __restrict__ intent,
    const float* __restrict__ Wq, const float* __restrict__ Wk,
    const float* __restrict__ Wv,
    const int* __restrict__ list_item, const int* __restrict__ list_int,
    const int* __restrict__ cnt,
    float* __restrict__ qb, float* __restrict__ kb, float* __restrict__ vb) {
  const int z = blockIdx.z;
  const int g = z / 9, B = z - g * 9;
  const float* X;  const float* W;  const int* list;  float* Y;  int n, Tmax;
  if (g == 0) { X = item;   W = Wq; list = list_item; Y = qb; n = min(cnt[B], T_ITEM);         Tmax = T_ITEM; }
  else if (g == 1) { X = intent; W = Wk; list = list_int;  Y = kb; n = min(cnt[NBUCK + B], T_INT); Tmax = T_INT; }
  else { X = intent; W = Wv; list = list_int;  Y = vb; n = min(cnt[NBUCK + B], T_INT); Tmax = T_INT; }

  const int row0 = blockIdx.y * TM;
  if (row0 >= n) return;                 // uniform across block
  const int rows = min(TM, n - row0);
  const int c0 = blockIdx.x * TN;
  const int t = (int)threadIdx.x;

  __shared__ float Xs[GBK][TM + 4];   // k-major (transposed on store)
  __shared__ float Ws[GBK][TN + 4];

  const int tokA = t >> 2;            // 0..127
  const int kqA  = (t & 3) * 4;       // 0,4,8,12
  const int liA  = clampi(list[row0 + min(tokA, rows - 1)], 0, Tmax - 1);
  const float* xrow = X + (size_t)liA * DMODEL;
  const int kW = t >> 5;              // 0..15
  const int cW = (t & 31) * 4;        // 0..124

  const int ty = t >> 5;              // row group (8 rows), 0..15
  const int tx = t & 31;              // col group (4 cols), 0..31

  float acc[8][4];
  #pragma unroll
  for (int i = 0; i < 8; ++i)
    #pragma unroll
    for (int j = 0; j < 4; ++j) acc[i][j] = 0.f;

  for (int k0 = 0; k0 < DMODEL; k0 += GBK) {
    float4 xa = *(const float4*)(xrow + k0 + kqA);
    const float* wp = W + ((size_t)B * DMODEL + k0 + kW) * (size_t)(NHEAD * DK) + c0 + cW;
    float4 wa = *(const float4*)wp;

    Xs[kqA + 0][tokA] = xa.x; Xs[kqA + 1][tokA] = xa.y;
    Xs[kqA + 2][tokA] = xa.z; Xs[kqA + 3][tokA] = xa.w;
    *(float4*)&Ws[kW][cW] = wa;
    __syncthreads();

    #pragma unroll
    for (int kk = 0; kk < GBK; ++kk) {
      float a[8], bv[4];
      *(float4*)&a[0]  = *(const float4*)&Xs[kk][ty * 8];
      *(float4*)&a[4]  = *(const float4*)&Xs[kk][ty * 8 + 4];
      *(float4*)&bv[0] = *(const float4*)&Ws[kk][tx * 4];
      #pragma unroll
      for (int i = 0; i < 8; ++i)
        #pragma unroll
        for (int j = 0; j < 4; ++j)
          acc[i][j] = fmaf(a[i], bv[j], acc[i][j]);
    }
    __syncthreads();
  }

  #pragma unroll
  for (int i = 0; i < 8; ++i) {
    const int r = ty * 8 + i;
    if (r < rows) {
      const int tok = clampi(list[row0 + r], 0, Tmax - 1);
      float* yr = Y + (size_t)tok * (size_t)(NHEAD * DK) + c0 + tx * 4;
      *(float4*)yr = make_float4(acc[i][0], acc[i][1], acc[i][2], acc[i][3]);
    }
  }
}

// ---------------------------------------------------------------------------
// Kernel 3: fused attention: scores -> softmax -> exact top-16 per segment ->
//           sparse p@V.  (index outputs come from the fp64 sidecar)
// Block = 256 thr (4 waves), 16 q-rows per block (4 per wave).
//
// Top-k rewrite vs previous version:
//  * 4 rows processed INTERLEAVED (4 independent shuffle chains -> swizzle
//    latency hidden; previously serial per row).
//  * segment 2: single 21-stage bitonic sort over 64 lanes (42 swizzles)
//    replaces 16 serial butterfly rounds (192 swizzles).
//  * segment 1: per-lane top-2 registers; the full 16-candidate rescan runs
//    only when a lane loses twice (expected ~2.5x/row instead of 16x/row).
// Extraction slots, tiebreak (max value, then min index) and all arithmetic
// are unchanged -> output bitwise identical to previous version.
// ---------------------------------------------------------------------------
__device__ __forceinline__ unsigned ordf(float v) {
  unsigned s = __float_as_uint(v);
  return s ^ ((unsigned)((int)s >> 31) | 0x80000000u);
}
__device__ __forceinline__ float unordf(unsigned u) {
  unsigned s = (u & 0x80000000u) ? (u ^ 0x80000000u) : ~u;
  return __uint_as_float(s);
}
__device__ __forceinline__ unsigned long long shfl_xor_u64(unsigned long long w, int off) {
  unsigned lo = __shfl_xor((unsigned)w, off);
  unsigned hi = __shfl_xor((unsigned)(w >> 32), off);
  return ((unsigned long long)hi << 32) | lo;
}

__global__ __launch_bounds__(256) void attn_kernel(
    const float* __restrict__ Q, const float* __restrict__ K,
    const float* __restrict__ V, float* __restrict__ outx) {
  const int b = blockIdx.z, h = blockIdx.y;
  const int n0 = blockIdx.x * 16;
  const int t = (int)threadIdx.x;
  const int wave = t >> 6, lane = t & 63;

  __shared__ float Qs[16][64];
  __shared__ float Ks[64][68];        // +4 pad: conflict-free b128
  __shared__ int   kept_m[16][32];
  __shared__ float kept_p[16][32];

  {
    const int r = t >> 4, k4 = (t & 15) * 4;
    *(float4*)&Qs[r][k4] =
        *(const float4*)(Q + (size_t)(b * SEQLEN + n0 + r) * (NHEAD * DK) + h * DK + k4);
  }
  __syncthreads();

  const int r0 = wave * 4;
  float sv[4][17];                    // static-indexed (unrolled loops only)

  #pragma unroll
  for (int c = 0; c < 17; ++c) {
    if (c > 0) __syncthreads();
    #pragma unroll
    for (int j = 0; j < 4; ++j) {
      const int row = (t >> 4) + 16 * j;
      const int k4 = (t & 15) * 4;
      *(float4*)&Ks[row][k4] =
          *(const float4*)(K + (size_t)(b * NN2 + c * 64 + row) * (NHEAD * DK) + h * DK + k4);
    }
    __syncthreads();

    float a0 = 0.f, a1 = 0.f, a2 = 0.f, a3 = 0.f;
    #pragma unroll 4
    for (int k4 = 0; k4 < 64; k4 += 4) {
      const float4 kv = *(const float4*)&Ks[lane][k4];
      const float4 q0 = *(const float4*)&Qs[r0 + 0][k4];   // wave-uniform: LDS broadcast
      const float4 q1 = *(const float4*)&Qs[r0 + 1][k4];
      const float4 q2 = *(const float4*)&Qs[r0 + 2][k4];
      const float4 q3 = *(const float4*)&Qs[r0 + 3][k4];
      a0 = fmaf(q0.x, kv.x, a0); a0 = fmaf(q0.y, kv.y, a0);
      a0 = fmaf(q0.z, kv.z, a0); a0 = fmaf(q0.w, kv.w, a0);
      a1 = fmaf(q1.x, kv.x, a1); a1 = fmaf(q1.y, kv.y, a1);
      a1 = fmaf(q1.z, kv.z, a1); a1 = fmaf(q1.w, kv.w, a1);
      a2 = fmaf(q2.x, kv.x, a2); a2 = fmaf(q2.y, kv.y, a2);
      a2 = fmaf(q2.z, kv.z, a2); a2 = fmaf(q2.w, kv.w, a2);
      a3 = fmaf(q3.x, kv.x, a3); a3 = fmaf(q3.y, kv.y, a3);
      a3 = fmaf(q3.z, kv.z, a3); a3 = fmaf(q3.w, kv.w, a3);
    }
    sv[0][c] = a0 * 0.125f; sv[1][c] = a1 * 0.125f;
    sv[2][c] = a2 * 0.125f; sv[3][c] = a3 * 0.125f;
  }

  // ---- softmax stats, 4 rows interleaved ----
  float M_[4], invL_[4];
  {
    float L_[4];
    #pragma unroll
    for (int r = 0; r < 4; ++r) {
      float M = -3.402823466e38f;
      #pragma unroll
      for (int c = 0; c < 17; ++c) M = fmaxf(M, sv[r][c]);
      M_[r] = M;
    }
    #pragma unroll
    for (int off = 32; off >= 1; off >>= 1) {
      #pragma unroll
      for (int r = 0; r < 4; ++r) M_[r] = fmaxf(M_[r], __shfl_xor(M_[r], off));
    }
    #pragma unroll
    for (int r = 0; r < 4; ++r) {
      float L = 0.f;
      #pragma unroll
      for (int c = 0; c < 17; ++c) L += __expf(sv[r][c] - M_[r]);
      L_[r] = L;
    }
    #pragma unroll
    for (int off = 32; off >= 1; off >>= 1) {
      #pragma unroll
      for (int r = 0; r < 4; ++r) L_[r] += __shfl_xor(L_[r], off);
    }
    #pragma unroll
    for (int r = 0; r < 4; ++r) invL_[r] = 1.0f / L_[r];
  }

  // ---- segment 1 keys + per-lane top-2 init ----
  unsigned kh[4][16];
  #pragma unroll
  for (int r = 0; r < 4; ++r)
    #pragma unroll
    for (int c = 0; c < 16; ++c) kh[r][c] = ordf(sv[r][c]);

  unsigned long long b1_[4], b2_[4];
  unsigned alive_[4];
  #pragma unroll
  for (int r = 0; r < 4; ++r) {
    unsigned long long b1 = 0ull, b2 = 0ull;
    #pragma unroll
    for (int c = 0; c < 16; ++c) {
      const unsigned long long k64 =
          ((unsigned long long)kh[r][c] << 32) | (unsigned)~(unsigned)(c * 64 + lane);
      const unsigned long long mn = (k64 < b1) ? k64 : b1;  // min(b1,k)
      b1 = (k64 > b1) ? k64 : b1;
      b2 = (mn > b2) ? mn : b2;
    }
    b1_[r] = b1; b2_[r] = b2; alive_[r] = 0xFFFFu;
  }

  // ---- segment 1: 16 extraction rounds, 4 rows interleaved ----
  for (int round = 0; round < TOPK; ++round) {
    unsigned long long w0 = b1_[0], w1 = b1_[1], w2 = b1_[2], w3 = b1_[3];
    #pragma unroll
    for (int off = 1; off < 64; off <<= 1) {
      unsigned long long o;
      o = shfl_xor_u64(w0, off); w0 = (o > w0) ? o : w0;
      o = shfl_xor_u64(w1, off); w1 = (o > w1) ? o : w1;
      o = shfl_xor_u64(w2, off); w2 = (o > w2) ? o : w2;
      o = shfl_xor_u64(w3, off); w3 = (o > w3) ? o : w3;
    }
    const unsigned long long ws[4] = {w0, w1, w2, w3};
    #pragma unroll
    for (int r = 0; r < 4; ++r) {
      const unsigned long long w = ws[r];
      const int m = (int)((~(unsigned)w) & 1023u);
      if (lane == round) {
        kept_m[r0 + r][round] = m;
        kept_p[r0 + r][round] = __expf(unordf((unsigned)(w >> 32)) - M_[r]) * invL_[r];
      }
      if ((m & 63) == lane) {          // winner lane bookkeeping
        alive_[r] &= ~(1u << (m >> 6));
        if (b2_[r]) { b1_[r] = b2_[r]; b2_[r] = 0ull; }
        else {
          unsigned long long mx = 0ull;
          #pragma unroll
          for (int c = 0; c < 16; ++c) {
            const unsigned long long k64 =
                ((unsigned long long)kh[r][c] << 32) | (unsigned)~(unsigned)(c * 64 + lane);
            if ((alive_[r] >> c) & 1u) mx = (k64 > mx) ? k64 : mx;
          }
          b1_[r] = mx;
        }
      }
    }
  }

  // ---- segment 2: bitonic sort (descending) of the 64 tail candidates ----
  {
    unsigned long long w_[4];
    #pragma unroll
    for (int r = 0; r < 4; ++r)
      w_[r] = ((unsigned long long)ordf(sv[r][16]) << 32) | (unsigned)~(unsigned)lane;
    #pragma unroll
    for (int k = 2; k <= 64; k <<= 1) {
      #pragma unroll
      for (int j = k >> 1; j >= 1; j >>= 1) {
        const bool tm = (((lane & j) != 0) == ((lane & k) != 0));
        #pragma unroll
        for (int r = 0; r < 4; ++r) {
          const unsigned long long o = shfl_xor_u64(w_[r], j);
          w_[r] = ((o > w_[r]) == tm) ? o : w_[r];
        }
      }
    }
    if (lane < TOPK) {
      #pragma unroll
      for (int r = 0; r < 4; ++r) {
        kept_m[r0 + r][TOPK + lane] = 1024 + (int)((~(unsigned)w_[r]) & 63u);
        kept_p[r0 + r][TOPK + lane] =
            __expf(unordf((unsigned)(w_[r] >> 32)) - M_[r]) * invL_[r];
      }
    }
  }
  __syncthreads();

  #pragma unroll
  for (int rr = 0; rr < 4; ++rr) {
    const int r_loc = wave * 4 + rr;
    const int n = n0 + r_loc;
    float x = 0.f;
    #pragma unroll
    for (int i = 0; i < 32; ++i) {
      const int m = clampi(kept_m[r_loc][i], 0, NN2 - 1);
      const float p = kept_p[r_loc][i];
      x = fmaf(p, V[(size_t)(b * NN2 + m) * (NHEAD * DK) + h * DK + lane], x);
    }
    outx[(size_t)(b * SEQLEN + n) * (NHEAD * DK) + h * DK + lane] = x;
  }
}

// ---------------------------------------------------------------------------
extern "C" void kernel_launch(void* const* d_in, const int* in_sizes, int n_in,
                              void* d_out, int out_size, void* d_ws, size_t ws_size,
                              hipStream_t stream) {
  const float* item    = (const float*)d_in[0];
  const float* intent  = (const float*)d_in[1];
  // d_in[2] = mask: constant all-True -> no-op, skipped
  const int*   b_seq   = (const int*)d_in[3];
  const int*   b_seq2  = (const int*)d_in[4];
  const float* W_item  = (const float*)d_in[5];   // [9][1024][16][64]
  const float* W_int   = (const float*)d_in[6];   // [2][9][1024][16][64]

  if (ws_size < WS_NEED) return;   // clean failure instead of device fault

  char* ws = (char*)d_ws;
  float* qb = (float*)(ws + Q_OFF);
  float* kb = (float*)(ws + K_OFF);
  float* vb = (float*)(ws + V_OFF);
  double* q0d = (double*)(ws + Q0D_OFF);   // aliases V region (used before v-GEMM)
  double* k0dT = (double*)(ws + K0D_OFF);  // transposed [64][T_INT]
  int* cnt       = (int*)(ws + CNT_OFF);
  int* list_item = (int*)(ws + LI_OFF);
  int* list_int  = (int*)(ws + LN_OFF);

  float* outx  = (float*)d_out;
  float* out_s = outx + X_OUT_ELEMS;
  float* out_a = out_s + SIDX_ELEMS;

  hipMemsetAsync(cnt, 0, 128, stream);
  bucketize_kernel<<<dim3(9), 256, 0, stream>>>(b_seq, b_seq2, cnt, list_item, list_int);

  // fp64 sidecar: head-0 q/k projections + exact argmax -> sIdx, aIdx.
  // k0 stored transposed so argmax reads are lane-coalesced.
  proj_head0_f64<<<dim3((T_ITEM + 3) / 4), 256, 0, stream>>>(item, W_item, b_seq, q0d, T_ITEM, 0);
  proj_head0_f64<<<dim3((T_INT + 3) / 4), 256, 0, stream>>>(intent, W_int, b_seq2, k0dT, T_INT, 1);
  argmax_f64<<<dim3(T_ITEM), 256, 0, stream>>>(q0d, k0dT, out_s, out_a);

  // fused fp32 q/k/v grouped GEMM (runs after argmax; v-write aliases sidecar)
  gemm_grouped_fused<<<dim3(8, 17, 27), 512, 0, stream>>>(
      item, intent,
      W_item, W_int, W_int + (size_t)NBUCK * DMODEL * (NHEAD * DK),
      list_item, list_int, cnt, qb, kb, vb);

  attn_kernel<<<dim3(SEQLEN / 16, NHEAD, BSZ), 256, 0, stream>>>(qb, kb, vb, outx);
}